// Round 11
// baseline (451.324 us; speedup 1.0000x reference)
//
#include <hip/hip_runtime.h>
#include <hip/hip_bf16.h>
#include <math.h>

typedef __hip_bfloat16 bf16;

#define NN 50000
#define EE 800000
#define EPB 4096   // edges per block (hist/scatter)
#define NBK 196    // dst buckets = ceil(NN/256); also blocks for hist/scatter
#define BCAP 6144  // max edges per bucket (mean 4096, sd ~64)

__device__ __forceinline__ float b2f(bf16 v) { return __bfloat162float(v); }
__device__ __forceinline__ float rcp_(float x) { return __builtin_amdgcn_rcpf(x); }
__device__ __forceinline__ float sigmoidf_(float x) { return rcp_(1.0f + __expf(-x)); }
__device__ __forceinline__ float tanhf_(float x) {
    float xx = fminf(fmaxf(x, -15.0f), 15.0f);
    float e = __expf(2.0f * xx);
    return (e - 1.0f) * rcp_(e + 1.0f);
}
__device__ __forceinline__ float leakyf_(float x) { return x > 0.0f ? x : 0.2f * x; }
__device__ __forceinline__ unsigned short f2bf(float f) {
    unsigned u = __float_as_uint(f);
    unsigned r = (u + 0x7FFFu + ((u >> 16) & 1u)) >> 16;
    return (unsigned short)r;
}
__device__ __forceinline__ unsigned pack2(float a, float b) {
    return (unsigned)f2bf(a) | ((unsigned)f2bf(b) << 16);
}
__device__ __forceinline__ float lo_(unsigned u) { return __uint_as_float(u << 16); }
__device__ __forceinline__ float hi_(unsigned u) { return __uint_as_float(u & 0xFFFF0000u); }

// weight-pool element offsets (fp32 pool in ws)
#define OFF_W1 0
#define OFF_B1 16384
#define OFF_W2 16512
#define OFF_B2 24704
#define OFF_W3 24768
#define OFF_B3 26816
#define OFF_GATW 26848
#define OFF_GAS 27872
#define OFF_GAD 27904
#define OFF_GAB 27936
#define OFF_WIHF 27968
#define OFF_BIHF 36160
#define OFF_BHHF 36416
#define OFF_WIHB 36672
#define OFF_BIHB 44864
#define OFF_BHHB 45120
#define OFF_GAMMA 45376
#define OFF_BETA 45504
#define OFF_FCW 45632
#define OFF_FCB 46912
#define WTOTAL 46922

// padded LSTM gate-weight layout: WG[32][416] (16 jc x 26, cols 24..25 zero-pad)
#define WGROW 416
#define WGTOT 13312

struct WSrc { const void* p[20]; };

// ---------------- dtype detection ----------------
__global__ void k_detect(const unsigned short* __restrict__ xraw,
                         const unsigned int* __restrict__ eraw, int* __restrict__ flags) {
    __shared__ int f32f, i64f;
    int t = threadIdx.x;
    if (t == 0) { f32f = 0; i64f = 1; }
    __syncthreads();
    for (int i = t; i < 4096; i += 256) {
        unsigned short u = xraw[i];
        int ex = (u >> 7) & 0xFF;
        if (ex >= 0xC0) atomicOr(&f32f, 1);
        if (eraw[2 * i + 1] != 0u) atomicAnd(&i64f, 0);
    }
    __syncthreads();
    if (t == 0) { flags[0] = f32f; flags[1] = i64f; }
}

// ---------------- weight conversion into fp32 pool ----------------
__global__ void k_cvt_w(WSrc srcs, float* __restrict__ dst, const int* __restrict__ flags,
                        int total) {
    constexpr int WOFF[21] = {OFF_W1,   OFF_B1,   OFF_W2,   OFF_B2,   OFF_W3,   OFF_B3,
                              OFF_GATW, OFF_GAS,  OFF_GAD,  OFF_GAB,  OFF_WIHF, OFF_BIHF,
                              OFF_BHHF, OFF_WIHB, OFF_BIHB, OFF_BHHB, OFF_GAMMA, OFF_BETA,
                              OFF_FCW,  OFF_FCB,  WTOTAL};
    int i = blockIdx.x * 256 + threadIdx.x;
    if (i >= total) return;
    int tn = 0;
#pragma unroll
    for (int j = 1; j < 20; ++j)
        if (i >= WOFF[j]) tn = j;
    int local = i - WOFF[tn];
    if (flags[0]) dst[i] = ((const float*)srcs.p[tn])[local];
    else dst[i] = b2f(((const bf16*)srcs.p[tn])[local]);
}

// ---------------- LSTM weight permutation: padded WG[32][416], BG[384] ------------------
// jc slot = 26 floats (24 used): col-in-slot = 3*r + g; feature f = jc*8+r; g: 0=i,1=c,2=o
__global__ void k_prep(const float* __restrict__ wp, float* __restrict__ wg,
                       float* __restrict__ bg) {
    int i = blockIdx.x * 256 + threadIdx.x;
    if (i < 384) {
        int jc = i / 24, rr = i % 24, r = rr / 3, g = rr % 3;
        int f = jc * 8 + r;
        int dir = f >> 6, j = f & 63;
        int grow = (g == 0) ? j : ((g == 1) ? 128 + j : 192 + j);
        int obi = dir ? OFF_BIHB : OFF_BIHF;
        int obh = dir ? OFF_BHHB : OFF_BHHF;
        bg[i] = wp[obi + grow] + wp[obh + grow];
    }
    if (i < WGTOT) {
        int k = i / WGROW, cc = i % WGROW;
        int jc = cc / 26, c = cc % 26;
        float v = 0.f;
        if (c < 24) {
            int r = c / 3, g = c % 3;
            int f = jc * 8 + r;
            int dir = f >> 6, j = f & 63;
            int grow = (g == 0) ? j : ((g == 1) ? 128 + j : 192 + j);
            int ow = dir ? OFF_WIHB : OFF_WIHF;
            v = wp[ow + grow * 32 + k];
        }
        wg[i] = v;
    }
}

// ---------------- bucketed CSR build ----------------
__global__ __launch_bounds__(256) void k_hist(const void* __restrict__ eraw,
                                              unsigned* __restrict__ gh,
                                              const int* __restrict__ flags) {
    __shared__ int h[256];
    int t = threadIdx.x, b = blockIdx.x;
    h[t] = 0;
    __syncthreads();
    int e0 = b * EPB;
    bool i64 = flags[1] != 0;
    for (int i = t; i < EPB; i += 256) {
        int e = e0 + i;
        if (e < EE) {
            int d = i64 ? (int)((const long long*)eraw)[EE + e] : ((const int*)eraw)[EE + e];
            d = min(max(d, 0), NN - 1);
            atomicAdd(&h[d >> 8], 1);
        }
    }
    __syncthreads();
    gh[b * 256 + t] = (unsigned)h[t];
}

__global__ __launch_bounds__(256) void k_bscan(const unsigned* __restrict__ gh,
                                               unsigned* __restrict__ gh2,
                                               int* __restrict__ bb, int* __restrict__ rptr) {
    __shared__ int s[256];
    int t = threadIdx.x;
    unsigned run = 0;
    for (int blk = 0; blk < NBK; ++blk) {
        unsigned v = gh[blk * 256 + t];
        gh2[blk * 256 + t] = run;
        run += v;
    }
    s[t] = (int)run;
    __syncthreads();
    for (int o = 1; o < 256; o <<= 1) {
        int x = (t >= o) ? s[t - o] : 0;
        __syncthreads();
        s[t] += x;
        __syncthreads();
    }
    bb[t] = s[t] - (int)run;
    if (t == 0) rptr[NN] = EE;
}

__global__ __launch_bounds__(256) void k_scatter(const void* __restrict__ eraw,
                                                 const unsigned* __restrict__ gh2,
                                                 const int* __restrict__ bb,
                                                 int2* __restrict__ ebkt,
                                                 const int* __restrict__ flags) {
    __shared__ unsigned cur[256];
    int t = threadIdx.x, b = blockIdx.x;
    cur[t] = gh2[b * 256 + t] + (unsigned)bb[t];
    __syncthreads();
    int e0 = b * EPB;
    bool i64 = flags[1] != 0;
    for (int i = t; i < EPB; i += 256) {
        int e = e0 + i;
        if (e < EE) {
            int sn, d;
            if (i64) {
                sn = (int)((const long long*)eraw)[e];
                d = (int)((const long long*)eraw)[EE + e];
            } else {
                sn = ((const int*)eraw)[e];
                d = ((const int*)eraw)[EE + e];
            }
            sn = min(max(sn, 0), NN - 1);
            d = min(max(d, 0), NN - 1);
            unsigned pos = atomicAdd(&cur[d >> 8], 1u);
            if (pos < (unsigned)EE) ebkt[pos] = make_int2(sn, d);
        }
    }
}

__global__ __launch_bounds__(256) void k_bucket_csr(const int2* __restrict__ ebkt,
                                                    const int* __restrict__ bb,
                                                    int* __restrict__ rptr,
                                                    float* __restrict__ dis,
                                                    int* __restrict__ csr_src) {
    __shared__ int hist[256];
    __shared__ int excl[256];
    __shared__ int cur[256];
    __shared__ int sorted[BCAP];
    int t = threadIdx.x, b = blockIdx.x;
    int s0 = bb[b], s1 = bb[b + 1];
    int len = min(s1 - s0, BCAP);
    hist[t] = 0;
    __syncthreads();
    for (int i = t; i < len; i += 256) atomicAdd(&hist[ebkt[s0 + i].y & 255], 1);
    __syncthreads();
    int v = hist[t];
    excl[t] = v;
    __syncthreads();
    for (int o = 1; o < 256; o <<= 1) {
        int x = (t >= o) ? excl[t - o] : 0;
        __syncthreads();
        excl[t] += x;
        __syncthreads();
    }
    int loc = excl[t] - v;
    int node = b * 256 + t;
    if (node < NN) {
        rptr[node] = s0 + loc;
        dis[node] = rsqrtf((float)(v + 1));
    }
    cur[t] = loc;
    __syncthreads();
    for (int i = t; i < len; i += 256) {
        int2 p = ebkt[s0 + i];
        int pos = atomicAdd(&cur[p.y & 255], 1);
        if (pos < BCAP) sorted[pos] = p.x;
    }
    __syncthreads();
    for (int i = t; i < len; i += 256) csr_src[s0 + i] = sorted[i];
}

// ---------------- LDS-tiled GEMM: C(bf16) = A @ W -------------------------------------
// MODE 0: A bf16; MODE 1: A fp32; MODE 2: runtime (flags[0] ? fp32 : bf16).
// SCALE: multiply output row by dis[node]. AVEC: also emit asrc/adst = C·a_src / C·a_dst.
template <int KIN, int KOUT, int MODE, bool SCALE, bool AVEC>
__global__ __launch_bounds__(256) void k_tile_mm(const void* __restrict__ A,
                                                 const float* __restrict__ W,
                                                 unsigned* __restrict__ C, int n,
                                                 const int* __restrict__ flags,
                                                 const float* __restrict__ dis,
                                                 const float* __restrict__ av,
                                                 float* __restrict__ asrc,
                                                 float* __restrict__ adst) {
    constexpr int BK = 32;
    constexpr int AST = BK + 4;
    constexpr int CPT = KOUT / 16;  // 8 / 4 / 2
    __shared__ float As[64 * AST];
    __shared__ float Ws[BK * KOUT];
    __shared__ float redS[AVEC ? 64 : 1];
    __shared__ float redD[AVEC ? 64 : 1];
    int t = threadIdx.x;
    int jc = t & 15;
    int ng = t >> 4;
    int base = blockIdx.x * 64;
    if (AVEC && t < 64) { redS[t] = 0.f; redD[t] = 0.f; }
    float acc[4][CPT];
#pragma unroll
    for (int i = 0; i < 4; ++i)
#pragma unroll
        for (int c = 0; c < CPT; ++c) acc[i][c] = 0.f;
    int snode = t >> 2;
    int gnode = min(base + snode, n - 1);
    int koff = (t & 3) * 8;
    bool f32 = (MODE == 1) || (MODE == 2 && flags[0] != 0);
    for (int k0 = 0; k0 < KIN; k0 += BK) {
        {
            const float4* src = (const float4*)(W + k0 * KOUT);
            float4* dst = (float4*)Ws;
#pragma unroll
            for (int p = 0; p < BK * KOUT / 1024; ++p) dst[t + p * 256] = src[t + p * 256];
        }
        if (!f32) {
            const unsigned* xr = (const unsigned*)A + (size_t)gnode * (KIN / 2) + (k0 + koff) / 2;
            unsigned u0 = xr[0], u1 = xr[1], u2 = xr[2], u3 = xr[3];
            float* d = As + snode * AST + koff;
            d[0] = lo_(u0); d[1] = hi_(u0);
            d[2] = lo_(u1); d[3] = hi_(u1);
            d[4] = lo_(u2); d[5] = hi_(u2);
            d[6] = lo_(u3); d[7] = hi_(u3);
        } else {
            const float4* ar = (const float4*)((const float*)A + (size_t)gnode * KIN + k0 + koff);
            float4 v0 = ar[0], v1 = ar[1];
            float4* d = (float4*)(As + snode * AST + koff);
            d[0] = v0;
            d[1] = v1;
        }
        __syncthreads();
#pragma unroll 8
        for (int k = 0; k < BK; ++k) {
            float w[CPT];
            const float* wr = Ws + k * KOUT + jc * CPT;
            if constexpr (CPT >= 4) {
#pragma unroll
                for (int c = 0; c < CPT; c += 4) {
                    float4 wv = *(const float4*)(wr + c);
                    w[c] = wv.x; w[c + 1] = wv.y; w[c + 2] = wv.z; w[c + 3] = wv.w;
                }
            } else {
                float2 wv = *(const float2*)wr;
                w[0] = wv.x; w[1] = wv.y;
            }
            float a0 = As[(ng * 4 + 0) * AST + k];
            float a1 = As[(ng * 4 + 1) * AST + k];
            float a2 = As[(ng * 4 + 2) * AST + k];
            float a3 = As[(ng * 4 + 3) * AST + k];
#pragma unroll
            for (int c = 0; c < CPT; ++c) {
                acc[0][c] += a0 * w[c];
                acc[1][c] += a1 * w[c];
                acc[2][c] += a2 * w[c];
                acc[3][c] += a3 * w[c];
            }
        }
        __syncthreads();
    }
#pragma unroll
    for (int i = 0; i < 4; ++i) {
        int node = base + ng * 4 + i;
        if (node < n) {
            float sc = SCALE ? dis[node] : 1.0f;
            unsigned* cr = C + (size_t)node * (KOUT / 2) + jc * (CPT / 2);
#pragma unroll
            for (int c = 0; c < CPT; c += 2)
                cr[c / 2] = pack2(acc[i][c] * sc, acc[i][c + 1] * sc);
        }
    }
    if constexpr (AVEC) {
#pragma unroll
        for (int i = 0; i < 4; ++i) {
            float psum = 0.f, pdum = 0.f;
#pragma unroll
            for (int c = 0; c < CPT; ++c) {
                psum += acc[i][c] * av[jc * CPT + c];
                pdum += acc[i][c] * av[32 + jc * CPT + c];
            }
            atomicAdd(&redS[ng * 4 + i], psum);
            atomicAdd(&redD[ng * 4 + i], pdum);
        }
        __syncthreads();
        if (t < 64) {
            int node = base + t;
            if (node < n) {
                asrc[node] = redS[t];
                adst[node] = redD[t];
            }
        }
    }
}

// ---------------- fused LSTM gates GEMM + nonlin + BN + FC ------------------------------
// Phase 1: gates = h @ WG + BG; WG padded 26/jc -> conflict-free b128 LDS reads.
// Phase 2: FC entirely in registers (padded fcwP reads + 16-lane shuffle reduction).
__global__ __launch_bounds__(256, 2) void k_gates_fc(const float* __restrict__ h,
                                                     const float* __restrict__ wg,
                                                     const float* __restrict__ bg,
                                                     const float* __restrict__ wp,
                                                     void* __restrict__ out,
                                                     const int* __restrict__ flags, int n) {
    __shared__ float smem[WGTOT + 64 * 36];  // Ws[13312] ++ As[2304] = 62464 B
    float* Ws = smem;
    float* As = smem + WGTOT;
    int t = threadIdx.x;
    int jc = t & 15, ng = t >> 4;
    int base = blockIdx.x * 64;
    {
        const float4* src = (const float4*)wg;
        float4* dst = (float4*)Ws;
#pragma unroll
        for (int p = 0; p < 13; ++p) dst[t + p * 256] = src[t + p * 256];
    }
    {
        int snode = t >> 2;
        int gnode = min(base + snode, n - 1);
        int koff = (t & 3) * 8;
        const float4* ar = (const float4*)(h + (size_t)gnode * 32 + koff);
        float4 v0 = ar[0], v1 = ar[1];
        float4* d = (float4*)(As + snode * 36 + koff);
        d[0] = v0;
        d[1] = v1;
    }
    float acc[4][24];
#pragma unroll
    for (int c = 0; c < 24; ++c) {
        float b = bg[jc * 24 + c];
        acc[0][c] = b; acc[1][c] = b; acc[2][c] = b; acc[3][c] = b;
    }
    float gsc[8], gbe[8];
    const float bnscale = rsqrtf(1.0f + 1e-5f);
#pragma unroll
    for (int rc = 0; rc < 8; ++rc) {
        gsc[rc] = wp[OFF_GAMMA + jc * 8 + rc] * bnscale;
        gbe[rc] = wp[OFF_BETA + jc * 8 + rc];
    }
    __syncthreads();
#pragma unroll 4
    for (int k = 0; k < 32; ++k) {
        float w[24];
        const float* wr = Ws + k * WGROW + jc * 26;
#pragma unroll
        for (int c = 0; c < 24; c += 4) {
            float4 wv = *(const float4*)(wr + c);
            w[c] = wv.x; w[c + 1] = wv.y; w[c + 2] = wv.z; w[c + 3] = wv.w;
        }
        float a0 = As[(ng * 4 + 0) * 36 + k];
        float a1 = As[(ng * 4 + 1) * 36 + k];
        float a2 = As[(ng * 4 + 2) * 36 + k];
        float a3 = As[(ng * 4 + 3) * 36 + k];
#pragma unroll
        for (int c = 0; c < 24; ++c) {
            acc[0][c] += a0 * w[c];
            acc[1][c] += a1 * w[c];
            acc[2][c] += a2 * w[c];
            acc[3][c] += a3 * w[c];
        }
    }
    // ---- phase 2: nonlin + BN + FC in registers ----
    __syncthreads();  // Ws/As dead
    float* fcwP = smem;  // [16][82]: fcwP[jc*82 + c*8 + rc] = fcW[c][jc*8+rc]; 82 -> distinct banks
    for (int i = t; i < 1312; i += 256) {
        int jcw = i / 82, c8 = i % 82;
        fcwP[i] = (c8 < 80) ? wp[OFF_FCW + (c8 >> 3) * 128 + jcw * 8 + (c8 & 7)] : 0.f;
    }
    __syncthreads();
    float p10[4][10];
#pragma unroll
    for (int i = 0; i < 4; ++i) {
        float vals[8];
#pragma unroll
        for (int rc = 0; rc < 8; ++rc) {
            float gi = acc[i][3 * rc], gc = acc[i][3 * rc + 1], go = acc[i][3 * rc + 2];
            float v = sigmoidf_(go) * tanhf_(sigmoidf_(gi) * tanhf_(gc));
            vals[rc] = v * gsc[rc] + gbe[rc];
        }
#pragma unroll
        for (int c = 0; c < 10; ++c) {
            float4 w0 = *(const float4*)(fcwP + jc * 82 + c * 8);
            float4 w1 = *(const float4*)(fcwP + jc * 82 + c * 8 + 4);
            p10[i][c] = vals[0] * w0.x + vals[1] * w0.y + vals[2] * w0.z + vals[3] * w0.w +
                        vals[4] * w1.x + vals[5] * w1.y + vals[6] * w1.z + vals[7] * w1.w;
        }
    }
#pragma unroll
    for (int off = 8; off >= 1; off >>= 1) {
#pragma unroll
        for (int i = 0; i < 4; ++i)
#pragma unroll
            for (int c = 0; c < 10; ++c)
                p10[i][c] += __shfl_down(p10[i][c], off, 16);
    }
    if (jc == 0) {
        bool f32o = flags[0] != 0;
#pragma unroll
        for (int i = 0; i < 4; ++i) {
            int node = base + ng * 4 + i;
            if (node < n) {
                if (f32o) {
                    float* o = (float*)out + (size_t)node * 10;
#pragma unroll
                    for (int c = 0; c < 10; ++c) o[c] = p10[i][c] + wp[OFF_FCB + c];
                } else {
                    bf16* o = (bf16*)out + (size_t)node * 10;
#pragma unroll
                    for (int c = 0; c < 10; ++c)
                        o[c] = __float2bfloat16(p10[i][c] + wp[OFF_FCB + c]);
                }
            }
        }
    }
}

// ---------------- GCN agg over pre-scaled t' (t*dis), bf16 gather -> fp32 out -----------
template <bool RELU>
__global__ void k_agg128(const unsigned* __restrict__ t, const int* __restrict__ rptr,
                         const int* __restrict__ csr_src, const float* __restrict__ dis,
                         const float* __restrict__ bias, float* __restrict__ out, int n) {
    int wave = (blockIdx.x * blockDim.x + threadIdx.x) >> 6;
    int lane = threadIdx.x & 63;
    if (wave >= n) return;
    int dst = wave;
    float dd = dis[dst];
    float ax, ay;
    {
        unsigned u = t[(size_t)dst * 64 + lane];
        ax = lo_(u);
        ay = hi_(u);
    }
    int s = __builtin_amdgcn_readfirstlane(max(0, min(rptr[dst], EE)));
    int e = __builtin_amdgcn_readfirstlane(max(s, min(rptr[dst + 1], EE)));
    int j = s;
    for (; j + 8 <= e; j += 8) {
        int i0 = csr_src[j], i1 = csr_src[j + 1], i2 = csr_src[j + 2], i3 = csr_src[j + 3];
        int i4 = csr_src[j + 4], i5 = csr_src[j + 5], i6 = csr_src[j + 6], i7 = csr_src[j + 7];
        unsigned u0 = t[(size_t)i0 * 64 + lane], u1 = t[(size_t)i1 * 64 + lane];
        unsigned u2 = t[(size_t)i2 * 64 + lane], u3 = t[(size_t)i3 * 64 + lane];
        unsigned u4 = t[(size_t)i4 * 64 + lane], u5 = t[(size_t)i5 * 64 + lane];
        unsigned u6 = t[(size_t)i6 * 64 + lane], u7 = t[(size_t)i7 * 64 + lane];
        ax += (lo_(u0) + lo_(u1)) + (lo_(u2) + lo_(u3)) + (lo_(u4) + lo_(u5)) + (lo_(u6) + lo_(u7));
        ay += (hi_(u0) + hi_(u1)) + (hi_(u2) + hi_(u3)) + (hi_(u4) + hi_(u5)) + (hi_(u6) + hi_(u7));
    }
    for (; j + 4 <= e; j += 4) {
        int i0 = csr_src[j], i1 = csr_src[j + 1], i2 = csr_src[j + 2], i3 = csr_src[j + 3];
        unsigned u0 = t[(size_t)i0 * 64 + lane], u1 = t[(size_t)i1 * 64 + lane];
        unsigned u2 = t[(size_t)i2 * 64 + lane], u3 = t[(size_t)i3 * 64 + lane];
        ax += (lo_(u0) + lo_(u1)) + (lo_(u2) + lo_(u3));
        ay += (hi_(u0) + hi_(u1)) + (hi_(u2) + hi_(u3));
    }
    for (; j < e; ++j) {
        unsigned u0 = t[(size_t)csr_src[j] * 64 + lane];
        ax += lo_(u0);
        ay += hi_(u0);
    }
    float2 bv = *(const float2*)(bias + 2 * lane);
    float vx = ax * dd + bv.x;
    float vy = ay * dd + bv.y;
    if (RELU) { vx = fmaxf(vx, 0.f); vy = fmaxf(vy, 0.f); }
    *(float2*)(out + (size_t)dst * 128 + 2 * lane) = make_float2(vx, vy);
}

// F=64: half-wave per edge, explicit 4-batches
template <bool RELU>
__global__ void k_agg64(const unsigned* __restrict__ t, const int* __restrict__ rptr,
                        const int* __restrict__ csr_src, const float* __restrict__ dis,
                        const float* __restrict__ bias, float* __restrict__ out, int n) {
    int wave = (blockIdx.x * blockDim.x + threadIdx.x) >> 6;
    int lane = threadIdx.x & 63;
    if (wave >= n) return;
    int dst = wave;
    int half = lane >> 5, l32 = lane & 31;
    float dd = dis[dst];
    float ax = 0.f, ay = 0.f;
    if (!half) {
        unsigned u = t[(size_t)dst * 32 + l32];
        ax = lo_(u);
        ay = hi_(u);
    }
    int s = max(0, min(rptr[dst], EE));
    int e = max(s, min(rptr[dst + 1], EE));
    int cnt = e - s;
    int pairs = cnt >> 1;
    int p = 0;
    for (; p + 4 <= pairs; p += 4) {
        int jb = s + 2 * p + half;
        int i0 = csr_src[jb], i1 = csr_src[jb + 2], i2 = csr_src[jb + 4], i3 = csr_src[jb + 6];
        unsigned u0 = t[(size_t)i0 * 32 + l32], u1 = t[(size_t)i1 * 32 + l32];
        unsigned u2 = t[(size_t)i2 * 32 + l32], u3 = t[(size_t)i3 * 32 + l32];
        ax += (lo_(u0) + lo_(u1)) + (lo_(u2) + lo_(u3));
        ay += (hi_(u0) + hi_(u1)) + (hi_(u2) + hi_(u3));
    }
    for (; p < pairs; ++p) {
        int i0 = csr_src[s + 2 * p + half];
        unsigned u0 = t[(size_t)i0 * 32 + l32];
        ax += lo_(u0);
        ay += hi_(u0);
    }
    if ((cnt & 1) && !half) {
        unsigned u0 = t[(size_t)csr_src[e - 1] * 32 + l32];
        ax += lo_(u0);
        ay += hi_(u0);
    }
    ax += __shfl_down(ax, 32);
    ay += __shfl_down(ay, 32);
    if (!half) {
        float2 bv = *(const float2*)(bias + 2 * l32);
        float vx = ax * dd + bv.x;
        float vy = ay * dd + bv.y;
        if (RELU) { vx = fmaxf(vx, 0.f); vy = fmaxf(vy, 0.f); }
        *(float2*)(out + (size_t)dst * 64 + 2 * l32) = make_float2(vx, vy);
    }
}

// F=32: quarter-wave per edge, explicit 4-batches
template <bool RELU>
__global__ void k_agg32(const unsigned* __restrict__ t, const int* __restrict__ rptr,
                        const int* __restrict__ csr_src, const float* __restrict__ dis,
                        const float* __restrict__ bias, float* __restrict__ out, int n) {
    int wave = (blockIdx.x * blockDim.x + threadIdx.x) >> 6;
    int lane = threadIdx.x & 63;
    if (wave >= n) return;
    int dst = wave;
    int q = lane >> 4, l16 = lane & 15;
    float dd = dis[dst];
    float ax = 0.f, ay = 0.f;
    if (q == 0) {
        unsigned u = t[(size_t)dst * 16 + l16];
        ax = lo_(u);
        ay = hi_(u);
    }
    int s = max(0, min(rptr[dst], EE));
    int e = max(s, min(rptr[dst + 1], EE));
    int cnt = e - s;
    int quads = cnt >> 2;
    int p = 0;
    for (; p + 4 <= quads; p += 4) {
        int jb = s + 4 * p + q;
        int i0 = csr_src[jb], i1 = csr_src[jb + 4], i2 = csr_src[jb + 8], i3 = csr_src[jb + 12];
        unsigned u0 = t[(size_t)i0 * 16 + l16], u1 = t[(size_t)i1 * 16 + l16];
        unsigned u2 = t[(size_t)i2 * 16 + l16], u3 = t[(size_t)i3 * 16 + l16];
        ax += (lo_(u0) + lo_(u1)) + (lo_(u2) + lo_(u3));
        ay += (hi_(u0) + hi_(u1)) + (hi_(u2) + hi_(u3));
    }
    for (; p < quads; ++p) {
        int i0 = csr_src[s + 4 * p + q];
        unsigned u0 = t[(size_t)i0 * 16 + l16];
        ax += lo_(u0);
        ay += hi_(u0);
    }
    int rem = cnt - 4 * quads;
    if (q < rem) {
        unsigned u0 = t[(size_t)csr_src[s + 4 * quads + q] * 16 + l16];
        ax += lo_(u0);
        ay += hi_(u0);
    }
    ax += __shfl_down(ax, 32);
    ay += __shfl_down(ay, 32);
    ax += __shfl_down(ax, 16);
    ay += __shfl_down(ay, 16);
    if (q == 0) {
        float2 bv = *(const float2*)(bias + 2 * l16);
        float vx = ax * dd + bv.x;
        float vy = ay * dd + bv.y;
        if (RELU) { vx = fmaxf(vx, 0.f); vy = fmaxf(vy, 0.f); }
        *(float2*)(out + (size_t)dst * 32 + 2 * l16) = make_float2(vx, vy);
    }
}

// ---------------- GAT aggregation (asrc/adst produced by the AVEC matmul) ---------------
__global__ void k_gat_agg(const unsigned* __restrict__ g, const int* __restrict__ rptr,
                          const int* __restrict__ csr_src, const float* __restrict__ asrc,
                          const float* __restrict__ adst, const float* __restrict__ gat_b,
                          float* __restrict__ out, int n) {
    int wave = (blockIdx.x * blockDim.x + threadIdx.x) >> 6;
    int lane = threadIdx.x & 63;
    if (wave >= n) return;
    int dst = wave;
    int q = lane >> 4, l16 = lane & 15;
    float ad = adst[dst];
    int s = max(0, min(rptr[dst], EE));
    int e = max(s, min(rptr[dst + 1], EE));
    float ax = 0.f, ay = 0.f, denom = 0.f;
    if (q == 0) {
        float w0 = __expf(fminf(leakyf_(asrc[dst] + ad), 80.f));
        unsigned u = g[(size_t)dst * 16 + l16];
        ax = lo_(u) * w0;
        ay = hi_(u) * w0;
        denom = w0;
    }
    int cnt = e - s;
    int quads = cnt >> 2;
    int p = 0;
    for (; p + 4 <= quads; p += 4) {
        int jb = s + 4 * p + q;
        int i0 = csr_src[jb], i1 = csr_src[jb + 4], i2 = csr_src[jb + 8], i3 = csr_src[jb + 12];
        float a0 = asrc[i0], a1 = asrc[i1], a2 = asrc[i2], a3 = asrc[i3];
        unsigned u0 = g[(size_t)i0 * 16 + l16], u1 = g[(size_t)i1 * 16 + l16];
        unsigned u2 = g[(size_t)i2 * 16 + l16], u3 = g[(size_t)i3 * 16 + l16];
        float w0 = __expf(fminf(leakyf_(a0 + ad), 80.f));
        float w1 = __expf(fminf(leakyf_(a1 + ad), 80.f));
        float w2 = __expf(fminf(leakyf_(a2 + ad), 80.f));
        float w3 = __expf(fminf(leakyf_(a3 + ad), 80.f));
        denom += (w0 + w1) + (w2 + w3);
        ax += lo_(u0) * w0 + lo_(u1) * w1 + lo_(u2) * w2 + lo_(u3) * w3;
        ay += hi_(u0) * w0 + hi_(u1) * w1 + hi_(u2) * w2 + hi_(u3) * w3;
    }
    for (; p < quads; ++p) {
        int i0 = csr_src[s + 4 * p + q];
        float wgt = __expf(fminf(leakyf_(asrc[i0] + ad), 80.f));
        unsigned u0 = g[(size_t)i0 * 16 + l16];
        denom += wgt;
        ax += lo_(u0) * wgt;
        ay += hi_(u0) * wgt;
    }
    int rem = cnt - 4 * quads;
    if (q < rem) {
        int i0 = csr_src[s + 4 * quads + q];
        float wgt = __expf(fminf(leakyf_(asrc[i0] + ad), 80.f));
        unsigned u0 = g[(size_t)i0 * 16 + l16];
        denom += wgt;
        ax += lo_(u0) * wgt;
        ay += hi_(u0) * wgt;
    }
    ax += __shfl_down(ax, 32);
    ay += __shfl_down(ay, 32);
    denom += __shfl_down(denom, 32);
    ax += __shfl_down(ax, 16);
    ay += __shfl_down(ay, 16);
    denom += __shfl_down(denom, 16);
    if (q == 0) {
        float r = rcp_(denom);
        float vx = fmaxf(ax * r + gat_b[2 * l16], 0.f);
        float vy = fmaxf(ay * r + gat_b[2 * l16 + 1], 0.f);
        *(float2*)(out + (size_t)dst * 32 + 2 * l16) = make_float2(vx, vy);
    }
}

// ---------------- launch ----------------
extern "C" void kernel_launch(void* const* d_in, const int* in_sizes, int n_in,
                              void* d_out, int out_size, void* d_ws, size_t ws_size,
                              hipStream_t stream) {
    const int N = NN;

    char* w = (char*)d_ws;
    auto alloc = [&](size_t bytes) {
        void* p = (void*)w;
        w += (bytes + 255) & ~(size_t)255;
        return p;
    };
    int* flags = (int*)alloc(256);
    float* wpool = (float*)alloc((size_t)WTOTAL * 4);
    float* wg = (float*)alloc((size_t)WGTOT * 4);
    float* bg = (float*)alloc(384 * 4);
    float* dis = (float*)alloc((size_t)N * 4);
    int* rptr = (int*)alloc((size_t)(N + 1) * 4);
    int* csr_src = (int*)alloc((size_t)EE * 4);
    unsigned* gh = (unsigned*)alloc((size_t)NBK * 256 * 4);
    unsigned* gh2 = (unsigned*)alloc((size_t)NBK * 256 * 4);
    int* bb = (int*)alloc(1024);
    int2* ebkt = (int2*)alloc((size_t)EE * 8);
    float* asrc = (float*)alloc((size_t)N * 4);
    float* adst = (float*)alloc((size_t)N * 4);
    float* hbuf = (float*)alloc((size_t)N * 32 * 4);       // fp32 N x 32 ping
    unsigned* bufT = (unsigned*)alloc((size_t)N * 64 * 4); // bf16 N x 128
    float* bufH = (float*)alloc((size_t)N * 128 * 4);      // fp32 N x 128

    WSrc ws_srcs;
    for (int i = 0; i < 20; ++i) ws_srcs.p[i] = d_in[2 + i];

    const int AGG = (N + 3) / 4;
    const int TMB = (N + 63) / 64;
    const int WB = (WTOTAL + 255) / 256;

    k_detect<<<1, 256, 0, stream>>>((const unsigned short*)d_in[0],
                                    (const unsigned int*)d_in[1], flags);
    k_cvt_w<<<WB, 256, 0, stream>>>(ws_srcs, wpool, flags, WTOTAL);
    k_prep<<<(WGTOT + 255) / 256, 256, 0, stream>>>(wpool, wg, bg);
    // bucketed CSR build
    k_hist<<<NBK, 256, 0, stream>>>(d_in[1], gh, flags);
    k_bscan<<<1, 256, 0, stream>>>(gh, gh2, bb, rptr);
    k_scatter<<<NBK, 256, 0, stream>>>(d_in[1], gh2, bb, ebkt, flags);
    k_bucket_csr<<<NBK, 256, 0, stream>>>(ebkt, bb, rptr, dis, csr_src);

    // GCN 1 (x -> t1' = (x@W1)*dis, bf16): runtime dtype select inside kernel
    k_tile_mm<128, 128, 2, true, false><<<TMB, 256, 0, stream>>>(
        d_in[0], wpool + OFF_W1, bufT, N, flags, dis, nullptr, nullptr, nullptr);
    k_agg128<true><<<AGG, 256, 0, stream>>>(bufT, rptr, csr_src, dis, wpool + OFF_B1, bufH, N);
    // GCN 2
    k_tile_mm<128, 64, 1, true, false><<<TMB, 256, 0, stream>>>(
        bufH, wpool + OFF_W2, bufT, N, flags, dis, nullptr, nullptr, nullptr);
    k_agg64<true><<<AGG, 256, 0, stream>>>(bufT, rptr, csr_src, dis, wpool + OFF_B2, bufH, N);
    // GCN 3
    k_tile_mm<64, 32, 1, true, false><<<TMB, 256, 0, stream>>>(
        bufH, wpool + OFF_W3, bufT, N, flags, dis, nullptr, nullptr, nullptr);
    k_agg32<false><<<AGG, 256, 0, stream>>>(bufT, rptr, csr_src, dis, wpool + OFF_B3, hbuf, N);
    // GAT matmul (unscaled) + fused attention-vector epilogue
    k_tile_mm<32, 32, 1, false, true><<<TMB, 256, 0, stream>>>(
        hbuf, wpool + OFF_GATW, bufT, N, flags, dis, wpool + OFF_GAS, asrc, adst);
    k_gat_agg<<<AGG, 256, 0, stream>>>(bufT, rptr, csr_src, asrc, adst, wpool + OFF_GAB, hbuf, N);
    // LSTM gates + nonlin + BN + FC (fused, writes d_out)
    k_gates_fc<<<TMB, 256, 0, stream>>>(hbuf, wg, bg, wpool, d_out, flags, N);
}

// Round 12
// 384.191 us; speedup vs baseline: 1.1747x; 1.1747x over previous
//
#include <hip/hip_runtime.h>
#include <hip/hip_bf16.h>
#include <math.h>

typedef __hip_bfloat16 bf16;

#define NN 50000
#define EE 800000
#define EPB 4096   // edges per block (hist/scatter)
#define NBK 196    // dst buckets = ceil(NN/256); also blocks for hist/scatter
#define BCAP 6144  // max edges per bucket (mean 4096, sd ~64)

__device__ __forceinline__ float b2f(bf16 v) { return __bfloat162float(v); }
__device__ __forceinline__ float rcp_(float x) { return __builtin_amdgcn_rcpf(x); }
__device__ __forceinline__ float sigmoidf_(float x) { return rcp_(1.0f + __expf(-x)); }
__device__ __forceinline__ float tanhf_(float x) {
    float xx = fminf(fmaxf(x, -15.0f), 15.0f);
    float e = __expf(2.0f * xx);
    return (e - 1.0f) * rcp_(e + 1.0f);
}
__device__ __forceinline__ float leakyf_(float x) { return x > 0.0f ? x : 0.2f * x; }
__device__ __forceinline__ unsigned short f2bf(float f) {
    unsigned u = __float_as_uint(f);
    unsigned r = (u + 0x7FFFu + ((u >> 16) & 1u)) >> 16;
    return (unsigned short)r;
}
__device__ __forceinline__ unsigned pack2(float a, float b) {
    return (unsigned)f2bf(a) | ((unsigned)f2bf(b) << 16);
}
__device__ __forceinline__ float lo_(unsigned u) { return __uint_as_float(u << 16); }
__device__ __forceinline__ float hi_(unsigned u) { return __uint_as_float(u & 0xFFFF0000u); }

// weight-pool element offsets (fp32 pool in ws)
#define OFF_W1 0
#define OFF_B1 16384
#define OFF_W2 16512
#define OFF_B2 24704
#define OFF_W3 24768
#define OFF_B3 26816
#define OFF_GATW 26848
#define OFF_GAS 27872
#define OFF_GAD 27904
#define OFF_GAB 27936
#define OFF_WIHF 27968
#define OFF_BIHF 36160
#define OFF_BHHF 36416
#define OFF_WIHB 36672
#define OFF_BIHB 44864
#define OFF_BHHB 45120
#define OFF_GAMMA 45376
#define OFF_BETA 45504
#define OFF_FCW 45632
#define OFF_FCB 46912
#define WTOTAL 46922

// padded LSTM gate-weight layout: WG[32][416] (16 jc x 26, cols 24..25 zero-pad)
// slot base = 104*jc bytes -> 8B aligned for all jc; bank residue 18*jc mod 32 all distinct
#define WGROW 416
#define WGTOT 13312

struct WSrc { const void* p[20]; };

// ---------------- dtype detection ----------------
__global__ void k_detect(const unsigned short* __restrict__ xraw,
                         const unsigned int* __restrict__ eraw, int* __restrict__ flags) {
    __shared__ int f32f, i64f;
    int t = threadIdx.x;
    if (t == 0) { f32f = 0; i64f = 1; }
    __syncthreads();
    for (int i = t; i < 4096; i += 256) {
        unsigned short u = xraw[i];
        int ex = (u >> 7) & 0xFF;
        if (ex >= 0xC0) atomicOr(&f32f, 1);
        if (eraw[2 * i + 1] != 0u) atomicAnd(&i64f, 0);
    }
    __syncthreads();
    if (t == 0) { flags[0] = f32f; flags[1] = i64f; }
}

// ---------------- weight conversion into fp32 pool ----------------
__global__ void k_cvt_w(WSrc srcs, float* __restrict__ dst, const int* __restrict__ flags,
                        int total) {
    constexpr int WOFF[21] = {OFF_W1,   OFF_B1,   OFF_W2,   OFF_B2,   OFF_W3,   OFF_B3,
                              OFF_GATW, OFF_GAS,  OFF_GAD,  OFF_GAB,  OFF_WIHF, OFF_BIHF,
                              OFF_BHHF, OFF_WIHB, OFF_BIHB, OFF_BHHB, OFF_GAMMA, OFF_BETA,
                              OFF_FCW,  OFF_FCB,  WTOTAL};
    int i = blockIdx.x * 256 + threadIdx.x;
    if (i >= total) return;
    int tn = 0;
#pragma unroll
    for (int j = 1; j < 20; ++j)
        if (i >= WOFF[j]) tn = j;
    int local = i - WOFF[tn];
    if (flags[0]) dst[i] = ((const float*)srcs.p[tn])[local];
    else dst[i] = b2f(((const bf16*)srcs.p[tn])[local]);
}

// ---------------- LSTM weight permutation: padded WG[32][416], BG[384] ------------------
// jc slot = 26 floats (24 used): col-in-slot = 3*r + g; feature f = jc*8+r; g: 0=i,1=c,2=o
__global__ void k_prep(const float* __restrict__ wp, float* __restrict__ wg,
                       float* __restrict__ bg) {
    int i = blockIdx.x * 256 + threadIdx.x;
    if (i < 384) {
        int jc = i / 24, rr = i % 24, r = rr / 3, g = rr % 3;
        int f = jc * 8 + r;
        int dir = f >> 6, j = f & 63;
        int grow = (g == 0) ? j : ((g == 1) ? 128 + j : 192 + j);
        int obi = dir ? OFF_BIHB : OFF_BIHF;
        int obh = dir ? OFF_BHHB : OFF_BHHF;
        bg[i] = wp[obi + grow] + wp[obh + grow];
    }
    if (i < WGTOT) {
        int k = i / WGROW, cc = i % WGROW;
        int jc = cc / 26, c = cc % 26;
        float v = 0.f;
        if (c < 24) {
            int r = c / 3, g = c % 3;
            int f = jc * 8 + r;
            int dir = f >> 6, j = f & 63;
            int grow = (g == 0) ? j : ((g == 1) ? 128 + j : 192 + j);
            int ow = dir ? OFF_WIHB : OFF_WIHF;
            v = wp[ow + grow * 32 + k];
        }
        wg[i] = v;
    }
}

// ---------------- bucketed CSR build ----------------
__global__ __launch_bounds__(256) void k_hist(const void* __restrict__ eraw,
                                              unsigned* __restrict__ gh,
                                              const int* __restrict__ flags) {
    __shared__ int h[256];
    int t = threadIdx.x, b = blockIdx.x;
    h[t] = 0;
    __syncthreads();
    int e0 = b * EPB;
    bool i64 = flags[1] != 0;
    for (int i = t; i < EPB; i += 256) {
        int e = e0 + i;
        if (e < EE) {
            int d = i64 ? (int)((const long long*)eraw)[EE + e] : ((const int*)eraw)[EE + e];
            d = min(max(d, 0), NN - 1);
            atomicAdd(&h[d >> 8], 1);
        }
    }
    __syncthreads();
    gh[b * 256 + t] = (unsigned)h[t];
}

__global__ __launch_bounds__(256) void k_bscan(const unsigned* __restrict__ gh,
                                               unsigned* __restrict__ gh2,
                                               int* __restrict__ bb, int* __restrict__ rptr) {
    __shared__ int s[256];
    int t = threadIdx.x;
    unsigned run = 0;
    for (int blk = 0; blk < NBK; ++blk) {
        unsigned v = gh[blk * 256 + t];
        gh2[blk * 256 + t] = run;
        run += v;
    }
    s[t] = (int)run;
    __syncthreads();
    for (int o = 1; o < 256; o <<= 1) {
        int x = (t >= o) ? s[t - o] : 0;
        __syncthreads();
        s[t] += x;
        __syncthreads();
    }
    bb[t] = s[t] - (int)run;
    if (t == 0) rptr[NN] = EE;
}

__global__ __launch_bounds__(256) void k_scatter(const void* __restrict__ eraw,
                                                 const unsigned* __restrict__ gh2,
                                                 const int* __restrict__ bb,
                                                 int2* __restrict__ ebkt,
                                                 const int* __restrict__ flags) {
    __shared__ unsigned cur[256];
    int t = threadIdx.x, b = blockIdx.x;
    cur[t] = gh2[b * 256 + t] + (unsigned)bb[t];
    __syncthreads();
    int e0 = b * EPB;
    bool i64 = flags[1] != 0;
    for (int i = t; i < EPB; i += 256) {
        int e = e0 + i;
        if (e < EE) {
            int sn, d;
            if (i64) {
                sn = (int)((const long long*)eraw)[e];
                d = (int)((const long long*)eraw)[EE + e];
            } else {
                sn = ((const int*)eraw)[e];
                d = ((const int*)eraw)[EE + e];
            }
            sn = min(max(sn, 0), NN - 1);
            d = min(max(d, 0), NN - 1);
            unsigned pos = atomicAdd(&cur[d >> 8], 1u);
            if (pos < (unsigned)EE) ebkt[pos] = make_int2(sn, d);
        }
    }
}

__global__ __launch_bounds__(256) void k_bucket_csr(const int2* __restrict__ ebkt,
                                                    const int* __restrict__ bb,
                                                    int* __restrict__ rptr,
                                                    float* __restrict__ dis,
                                                    int* __restrict__ csr_src) {
    __shared__ int hist[256];
    __shared__ int excl[256];
    __shared__ int cur[256];
    __shared__ int sorted[BCAP];
    int t = threadIdx.x, b = blockIdx.x;
    int s0 = bb[b], s1 = bb[b + 1];
    int len = min(s1 - s0, BCAP);
    hist[t] = 0;
    __syncthreads();
    for (int i = t; i < len; i += 256) atomicAdd(&hist[ebkt[s0 + i].y & 255], 1);
    __syncthreads();
    int v = hist[t];
    excl[t] = v;
    __syncthreads();
    for (int o = 1; o < 256; o <<= 1) {
        int x = (t >= o) ? excl[t - o] : 0;
        __syncthreads();
        excl[t] += x;
        __syncthreads();
    }
    int loc = excl[t] - v;
    int node = b * 256 + t;
    if (node < NN) {
        rptr[node] = s0 + loc;
        dis[node] = rsqrtf((float)(v + 1));
    }
    cur[t] = loc;
    __syncthreads();
    for (int i = t; i < len; i += 256) {
        int2 p = ebkt[s0 + i];
        int pos = atomicAdd(&cur[p.y & 255], 1);
        if (pos < BCAP) sorted[pos] = p.x;
    }
    __syncthreads();
    for (int i = t; i < len; i += 256) csr_src[s0 + i] = sorted[i];
}

// ---------------- LDS-tiled GEMM: C(bf16) = A @ W -------------------------------------
// MODE 0: A bf16; MODE 1: A fp32; MODE 2: runtime (flags[0] ? fp32 : bf16).
// SCALE: multiply output row by dis[node]. AVEC: also emit asrc/adst = C·a_src / C·a_dst.
template <int KIN, int KOUT, int MODE, bool SCALE, bool AVEC>
__global__ __launch_bounds__(256) void k_tile_mm(const void* __restrict__ A,
                                                 const float* __restrict__ W,
                                                 unsigned* __restrict__ C, int n,
                                                 const int* __restrict__ flags,
                                                 const float* __restrict__ dis,
                                                 const float* __restrict__ av,
                                                 float* __restrict__ asrc,
                                                 float* __restrict__ adst) {
    constexpr int BK = 32;
    constexpr int AST = BK + 4;
    constexpr int CPT = KOUT / 16;  // 8 / 4 / 2
    __shared__ float As[64 * AST];
    __shared__ float Ws[BK * KOUT];
    __shared__ float redS[AVEC ? 64 : 1];
    __shared__ float redD[AVEC ? 64 : 1];
    int t = threadIdx.x;
    int jc = t & 15;
    int ng = t >> 4;
    int base = blockIdx.x * 64;
    if (AVEC && t < 64) { redS[t] = 0.f; redD[t] = 0.f; }
    float acc[4][CPT];
#pragma unroll
    for (int i = 0; i < 4; ++i)
#pragma unroll
        for (int c = 0; c < CPT; ++c) acc[i][c] = 0.f;
    int snode = t >> 2;
    int gnode = min(base + snode, n - 1);
    int koff = (t & 3) * 8;
    bool f32 = (MODE == 1) || (MODE == 2 && flags[0] != 0);
    for (int k0 = 0; k0 < KIN; k0 += BK) {
        {
            const float4* src = (const float4*)(W + k0 * KOUT);
            float4* dst = (float4*)Ws;
#pragma unroll
            for (int p = 0; p < BK * KOUT / 1024; ++p) dst[t + p * 256] = src[t + p * 256];
        }
        if (!f32) {
            const unsigned* xr = (const unsigned*)A + (size_t)gnode * (KIN / 2) + (k0 + koff) / 2;
            unsigned u0 = xr[0], u1 = xr[1], u2 = xr[2], u3 = xr[3];
            float* d = As + snode * AST + koff;
            d[0] = lo_(u0); d[1] = hi_(u0);
            d[2] = lo_(u1); d[3] = hi_(u1);
            d[4] = lo_(u2); d[5] = hi_(u2);
            d[6] = lo_(u3); d[7] = hi_(u3);
        } else {
            const float4* ar = (const float4*)((const float*)A + (size_t)gnode * KIN + k0 + koff);
            float4 v0 = ar[0], v1 = ar[1];
            float4* d = (float4*)(As + snode * AST + koff);
            d[0] = v0;
            d[1] = v1;
        }
        __syncthreads();
#pragma unroll 8
        for (int k = 0; k < BK; ++k) {
            float w[CPT];
            const float* wr = Ws + k * KOUT + jc * CPT;
            if constexpr (CPT >= 4) {
#pragma unroll
                for (int c = 0; c < CPT; c += 4) {
                    float4 wv = *(const float4*)(wr + c);
                    w[c] = wv.x; w[c + 1] = wv.y; w[c + 2] = wv.z; w[c + 3] = wv.w;
                }
            } else {
                float2 wv = *(const float2*)wr;
                w[0] = wv.x; w[1] = wv.y;
            }
            float a0 = As[(ng * 4 + 0) * AST + k];
            float a1 = As[(ng * 4 + 1) * AST + k];
            float a2 = As[(ng * 4 + 2) * AST + k];
            float a3 = As[(ng * 4 + 3) * AST + k];
#pragma unroll
            for (int c = 0; c < CPT; ++c) {
                acc[0][c] += a0 * w[c];
                acc[1][c] += a1 * w[c];
                acc[2][c] += a2 * w[c];
                acc[3][c] += a3 * w[c];
            }
        }
        __syncthreads();
    }
#pragma unroll
    for (int i = 0; i < 4; ++i) {
        int node = base + ng * 4 + i;
        if (node < n) {
            float sc = SCALE ? dis[node] : 1.0f;
            unsigned* cr = C + (size_t)node * (KOUT / 2) + jc * (CPT / 2);
#pragma unroll
            for (int c = 0; c < CPT; c += 2)
                cr[c / 2] = pack2(acc[i][c] * sc, acc[i][c + 1] * sc);
        }
    }
    if constexpr (AVEC) {
#pragma unroll
        for (int i = 0; i < 4; ++i) {
            float psum = 0.f, pdum = 0.f;
#pragma unroll
            for (int c = 0; c < CPT; ++c) {
                psum += acc[i][c] * av[jc * CPT + c];
                pdum += acc[i][c] * av[32 + jc * CPT + c];
            }
            atomicAdd(&redS[ng * 4 + i], psum);
            atomicAdd(&redD[ng * 4 + i], pdum);
        }
        __syncthreads();
        if (t < 64) {
            int node = base + t;
            if (node < n) {
                asrc[node] = redS[t];
                adst[node] = redD[t];
            }
        }
    }
}

// ---------------- fused LSTM gates GEMM + nonlin + BN + FC ------------------------------
// Phase 1: gates = h @ WG + BG; padded WG (26/jc) read via float2 -> 8B-aligned ds_read_b64,
//          bank residues all distinct -> conflict-free AND aligned.
// Phase 2: LDS-based FC (b32 reads, alignment-safe) -> d_out.
__global__ __launch_bounds__(256, 2) void k_gates_fc(const float* __restrict__ h,
                                                     const float* __restrict__ wg,
                                                     const float* __restrict__ bg,
                                                     const float* __restrict__ wp,
                                                     void* __restrict__ out,
                                                     const int* __restrict__ flags, int n) {
    __shared__ float smem[WGTOT + 64 * 36];  // Ws[13312] ++ As[2304] = 62464 B
    float* Ws = smem;
    float* As = smem + WGTOT;
    int t = threadIdx.x;
    int jc = t & 15, ng = t >> 4;
    int base = blockIdx.x * 64;
    {
        const float4* src = (const float4*)wg;
        float4* dst = (float4*)Ws;
#pragma unroll
        for (int p = 0; p < 13; ++p) dst[t + p * 256] = src[t + p * 256];
    }
    {
        int snode = t >> 2;
        int gnode = min(base + snode, n - 1);
        int koff = (t & 3) * 8;
        const float4* ar = (const float4*)(h + (size_t)gnode * 32 + koff);
        float4 v0 = ar[0], v1 = ar[1];
        float4* d = (float4*)(As + snode * 36 + koff);
        d[0] = v0;
        d[1] = v1;
    }
    float acc[4][24];
#pragma unroll
    for (int c = 0; c < 24; ++c) {
        float b = bg[jc * 24 + c];
        acc[0][c] = b; acc[1][c] = b; acc[2][c] = b; acc[3][c] = b;
    }
    float gsc[8], gbe[8];
    const float bnscale = rsqrtf(1.0f + 1e-5f);
#pragma unroll
    for (int rc = 0; rc < 8; ++rc) {
        gsc[rc] = wp[OFF_GAMMA + jc * 8 + rc] * bnscale;
        gbe[rc] = wp[OFF_BETA + jc * 8 + rc];
    }
    __syncthreads();
#pragma unroll 4
    for (int k = 0; k < 32; ++k) {
        float w[24];
        const float* wr = Ws + k * WGROW + jc * 26;
#pragma unroll
        for (int c = 0; c < 24; c += 2) {
            float2 wv = *(const float2*)(wr + c);  // 8B-aligned for all jc
            w[c] = wv.x;
            w[c + 1] = wv.y;
        }
        float a0 = As[(ng * 4 + 0) * 36 + k];
        float a1 = As[(ng * 4 + 1) * 36 + k];
        float a2 = As[(ng * 4 + 2) * 36 + k];
        float a3 = As[(ng * 4 + 3) * 36 + k];
#pragma unroll
        for (int c = 0; c < 24; ++c) {
            acc[0][c] += a0 * w[c];
            acc[1][c] += a1 * w[c];
            acc[2][c] += a2 * w[c];
            acc[3][c] += a3 * w[c];
        }
    }
    // ---- phase 2: nonlin + BN -> rt (LDS), then FC (round-10 structure) ----
    __syncthreads();  // Ws/As dead; alias for phase 2
    float* rt = smem;           // 64 x 132 = 8448
    float* fcw = smem + 8448;   // 1280
    float* ps = smem + 9728;    // 64 x 40 = 2560  (ends at 12288)
#pragma unroll
    for (int i = 0; i < 4; ++i) {
        int nd = ng * 4 + i;
        float vals[8];
#pragma unroll
        for (int rc = 0; rc < 8; ++rc) {
            float gi = acc[i][3 * rc], gc = acc[i][3 * rc + 1], go = acc[i][3 * rc + 2];
            float v = sigmoidf_(go) * tanhf_(sigmoidf_(gi) * tanhf_(gc));
            vals[rc] = v * gsc[rc] + gbe[rc];
        }
        float* rr = rt + nd * 132 + jc * 8;
        *(float4*)rr = make_float4(vals[0], vals[1], vals[2], vals[3]);
        *(float4*)(rr + 4) = make_float4(vals[4], vals[5], vals[6], vals[7]);
    }
    for (int i = t; i < 1280; i += 256) fcw[i] = wp[OFF_FCW + i];
    __syncthreads();
    {
        int nd = t >> 2, q = t & 3;
        float p[10];
#pragma unroll
        for (int c = 0; c < 10; ++c) p[c] = 0.f;
#pragma unroll
        for (int k = 0; k < 32; ++k) {
            float rv = rt[nd * 132 + q * 32 + k];
#pragma unroll
            for (int c = 0; c < 10; ++c) p[c] += rv * fcw[c * 128 + q * 32 + k];
        }
#pragma unroll
        for (int c = 0; c < 10; ++c) ps[nd * 40 + q * 10 + c] = p[c];
    }
    __syncthreads();
    for (int idx = t; idx < 640; idx += 256) {
        int nd = idx / 10, c = idx % 10;
        int node = base + nd;
        if (node < n) {
            float v = wp[OFF_FCB + c] + ps[nd * 40 + c] + ps[nd * 40 + 10 + c] +
                      ps[nd * 40 + 20 + c] + ps[nd * 40 + 30 + c];
            if (flags[0]) ((float*)out)[(size_t)node * 10 + c] = v;
            else ((bf16*)out)[(size_t)node * 10 + c] = __float2bfloat16(v);
        }
    }
}

// ---------------- GCN agg over pre-scaled t' (t*dis), bf16 gather -> fp32 out -----------
template <bool RELU>
__global__ void k_agg128(const unsigned* __restrict__ t, const int* __restrict__ rptr,
                         const int* __restrict__ csr_src, const float* __restrict__ dis,
                         const float* __restrict__ bias, float* __restrict__ out, int n) {
    int wave = (blockIdx.x * blockDim.x + threadIdx.x) >> 6;
    int lane = threadIdx.x & 63;
    if (wave >= n) return;
    int dst = wave;
    float dd = dis[dst];
    float ax, ay;
    {
        unsigned u = t[(size_t)dst * 64 + lane];
        ax = lo_(u);
        ay = hi_(u);
    }
    int s = __builtin_amdgcn_readfirstlane(max(0, min(rptr[dst], EE)));
    int e = __builtin_amdgcn_readfirstlane(max(s, min(rptr[dst + 1], EE)));
    int j = s;
    for (; j + 8 <= e; j += 8) {
        int i0 = csr_src[j], i1 = csr_src[j + 1], i2 = csr_src[j + 2], i3 = csr_src[j + 3];
        int i4 = csr_src[j + 4], i5 = csr_src[j + 5], i6 = csr_src[j + 6], i7 = csr_src[j + 7];
        unsigned u0 = t[(size_t)i0 * 64 + lane], u1 = t[(size_t)i1 * 64 + lane];
        unsigned u2 = t[(size_t)i2 * 64 + lane], u3 = t[(size_t)i3 * 64 + lane];
        unsigned u4 = t[(size_t)i4 * 64 + lane], u5 = t[(size_t)i5 * 64 + lane];
        unsigned u6 = t[(size_t)i6 * 64 + lane], u7 = t[(size_t)i7 * 64 + lane];
        ax += (lo_(u0) + lo_(u1)) + (lo_(u2) + lo_(u3)) + (lo_(u4) + lo_(u5)) + (lo_(u6) + lo_(u7));
        ay += (hi_(u0) + hi_(u1)) + (hi_(u2) + hi_(u3)) + (hi_(u4) + hi_(u5)) + (hi_(u6) + hi_(u7));
    }
    for (; j + 4 <= e; j += 4) {
        int i0 = csr_src[j], i1 = csr_src[j + 1], i2 = csr_src[j + 2], i3 = csr_src[j + 3];
        unsigned u0 = t[(size_t)i0 * 64 + lane], u1 = t[(size_t)i1 * 64 + lane];
        unsigned u2 = t[(size_t)i2 * 64 + lane], u3 = t[(size_t)i3 * 64 + lane];
        ax += (lo_(u0) + lo_(u1)) + (lo_(u2) + lo_(u3));
        ay += (hi_(u0) + hi_(u1)) + (hi_(u2) + hi_(u3));
    }
    for (; j < e; ++j) {
        unsigned u0 = t[(size_t)csr_src[j] * 64 + lane];
        ax += lo_(u0);
        ay += hi_(u0);
    }
    float2 bv = *(const float2*)(bias + 2 * lane);
    float vx = ax * dd + bv.x;
    float vy = ay * dd + bv.y;
    if (RELU) { vx = fmaxf(vx, 0.f); vy = fmaxf(vy, 0.f); }
    *(float2*)(out + (size_t)dst * 128 + 2 * lane) = make_float2(vx, vy);
}

// F=64: half-wave per edge, explicit 4-batches
template <bool RELU>
__global__ void k_agg64(const unsigned* __restrict__ t, const int* __restrict__ rptr,
                        const int* __restrict__ csr_src, const float* __restrict__ dis,
                        const float* __restrict__ bias, float* __restrict__ out, int n) {
    int wave = (blockIdx.x * blockDim.x + threadIdx.x) >> 6;
    int lane = threadIdx.x & 63;
    if (wave >= n) return;
    int dst = wave;
    int half = lane >> 5, l32 = lane & 31;
    float dd = dis[dst];
    float ax = 0.f, ay = 0.f;
    if (!half) {
        unsigned u = t[(size_t)dst * 32 + l32];
        ax = lo_(u);
        ay = hi_(u);
    }
    int s = max(0, min(rptr[dst], EE));
    int e = max(s, min(rptr[dst + 1], EE));
    int cnt = e - s;
    int pairs = cnt >> 1;
    int p = 0;
    for (; p + 4 <= pairs; p += 4) {
        int jb = s + 2 * p + half;
        int i0 = csr_src[jb], i1 = csr_src[jb + 2], i2 = csr_src[jb + 4], i3 = csr_src[jb + 6];
        unsigned u0 = t[(size_t)i0 * 32 + l32], u1 = t[(size_t)i1 * 32 + l32];
        unsigned u2 = t[(size_t)i2 * 32 + l32], u3 = t[(size_t)i3 * 32 + l32];
        ax += (lo_(u0) + lo_(u1)) + (lo_(u2) + lo_(u3));
        ay += (hi_(u0) + hi_(u1)) + (hi_(u2) + hi_(u3));
    }
    for (; p < pairs; ++p) {
        int i0 = csr_src[s + 2 * p + half];
        unsigned u0 = t[(size_t)i0 * 32 + l32];
        ax += lo_(u0);
        ay += hi_(u0);
    }
    if ((cnt & 1) && !half) {
        unsigned u0 = t[(size_t)csr_src[e - 1] * 32 + l32];
        ax += lo_(u0);
        ay += hi_(u0);
    }
    ax += __shfl_down(ax, 32);
    ay += __shfl_down(ay, 32);
    if (!half) {
        float2 bv = *(const float2*)(bias + 2 * l32);
        float vx = ax * dd + bv.x;
        float vy = ay * dd + bv.y;
        if (RELU) { vx = fmaxf(vx, 0.f); vy = fmaxf(vy, 0.f); }
        *(float2*)(out + (size_t)dst * 64 + 2 * l32) = make_float2(vx, vy);
    }
}

// F=32: quarter-wave per edge, explicit 4-batches
template <bool RELU>
__global__ void k_agg32(const unsigned* __restrict__ t, const int* __restrict__ rptr,
                        const int* __restrict__ csr_src, const float* __restrict__ dis,
                        const float* __restrict__ bias, float* __restrict__ out, int n) {
    int wave = (blockIdx.x * blockDim.x + threadIdx.x) >> 6;
    int lane = threadIdx.x & 63;
    if (wave >= n) return;
    int dst = wave;
    int q = lane >> 4, l16 = lane & 15;
    float dd = dis[dst];
    float ax = 0.f, ay = 0.f;
    if (q == 0) {
        unsigned u = t[(size_t)dst * 16 + l16];
        ax = lo_(u);
        ay = hi_(u);
    }
    int s = max(0, min(rptr[dst], EE));
    int e = max(s, min(rptr[dst + 1], EE));
    int cnt = e - s;
    int quads = cnt >> 2;
    int p = 0;
    for (; p + 4 <= quads; p += 4) {
        int jb = s + 4 * p + q;
        int i0 = csr_src[jb], i1 = csr_src[jb + 4], i2 = csr_src[jb + 8], i3 = csr_src[jb + 12];
        unsigned u0 = t[(size_t)i0 * 16 + l16], u1 = t[(size_t)i1 * 16 + l16];
        unsigned u2 = t[(size_t)i2 * 16 + l16], u3 = t[(size_t)i3 * 16 + l16];
        ax += (lo_(u0) + lo_(u1)) + (lo_(u2) + lo_(u3));
        ay += (hi_(u0) + hi_(u1)) + (hi_(u2) + hi_(u3));
    }
    for (; p < quads; ++p) {
        int i0 = csr_src[s + 4 * p + q];
        unsigned u0 = t[(size_t)i0 * 16 + l16];
        ax += lo_(u0);
        ay += hi_(u0);
    }
    int rem = cnt - 4 * quads;
    if (q < rem) {
        unsigned u0 = t[(size_t)csr_src[s + 4 * quads + q] * 16 + l16];
        ax += lo_(u0);
        ay += hi_(u0);
    }
    ax += __shfl_down(ax, 32);
    ay += __shfl_down(ay, 32);
    ax += __shfl_down(ax, 16);
    ay += __shfl_down(ay, 16);
    if (q == 0) {
        float2 bv = *(const float2*)(bias + 2 * l16);
        float vx = ax * dd + bv.x;
        float vy = ay * dd + bv.y;
        if (RELU) { vx = fmaxf(vx, 0.f); vy = fmaxf(vy, 0.f); }
        *(float2*)(out + (size_t)dst * 32 + 2 * l16) = make_float2(vx, vy);
    }
}

// ---------------- GAT aggregation (asrc/adst produced by the AVEC matmul) ---------------
__global__ void k_gat_agg(const unsigned* __restrict__ g, const int* __restrict__ rptr,
                          const int* __restrict__ csr_src, const float* __restrict__ asrc,
                          const float* __restrict__ adst, const float* __restrict__ gat_b,
                          float* __restrict__ out, int n) {
    int wave = (blockIdx.x * blockDim.x + threadIdx.x) >> 6;
    int lane = threadIdx.x & 63;
    if (wave >= n) return;
    int dst = wave;
    int q = lane >> 4, l16 = lane & 15;
    float ad = adst[dst];
    int s = max(0, min(rptr[dst], EE));
    int e = max(s, min(rptr[dst + 1], EE));
    float ax = 0.f, ay = 0.f, denom = 0.f;
    if (q == 0) {
        float w0 = __expf(fminf(leakyf_(asrc[dst] + ad), 80.f));
        unsigned u = g[(size_t)dst * 16 + l16];
        ax = lo_(u) * w0;
        ay = hi_(u) * w0;
        denom = w0;
    }
    int cnt = e - s;
    int quads = cnt >> 2;
    int p = 0;
    for (; p + 4 <= quads; p += 4) {
        int jb = s + 4 * p + q;
        int i0 = csr_src[jb], i1 = csr_src[jb + 4], i2 = csr_src[jb + 8], i3 = csr_src[jb + 12];
        float a0 = asrc[i0], a1 = asrc[i1], a2 = asrc[i2], a3 = asrc[i3];
        unsigned u0 = g[(size_t)i0 * 16 + l16], u1 = g[(size_t)i1 * 16 + l16];
        unsigned u2 = g[(size_t)i2 * 16 + l16], u3 = g[(size_t)i3 * 16 + l16];
        float w0 = __expf(fminf(leakyf_(a0 + ad), 80.f));
        float w1 = __expf(fminf(leakyf_(a1 + ad), 80.f));
        float w2 = __expf(fminf(leakyf_(a2 + ad), 80.f));
        float w3 = __expf(fminf(leakyf_(a3 + ad), 80.f));
        denom += (w0 + w1) + (w2 + w3);
        ax += lo_(u0) * w0 + lo_(u1) * w1 + lo_(u2) * w2 + lo_(u3) * w3;
        ay += hi_(u0) * w0 + hi_(u1) * w1 + hi_(u2) * w2 + hi_(u3) * w3;
    }
    for (; p < quads; ++p) {
        int i0 = csr_src[s + 4 * p + q];
        float wgt = __expf(fminf(leakyf_(asrc[i0] + ad), 80.f));
        unsigned u0 = g[(size_t)i0 * 16 + l16];
        denom += wgt;
        ax += lo_(u0) * wgt;
        ay += hi_(u0) * wgt;
    }
    int rem = cnt - 4 * quads;
    if (q < rem) {
        int i0 = csr_src[s + 4 * quads + q];
        float wgt = __expf(fminf(leakyf_(asrc[i0] + ad), 80.f));
        unsigned u0 = g[(size_t)i0 * 16 + l16];
        denom += wgt;
        ax += lo_(u0) * wgt;
        ay += hi_(u0) * wgt;
    }
    ax += __shfl_down(ax, 32);
    ay += __shfl_down(ay, 32);
    denom += __shfl_down(denom, 32);
    ax += __shfl_down(ax, 16);
    ay += __shfl_down(ay, 16);
    denom += __shfl_down(denom, 16);
    if (q == 0) {
        float r = rcp_(denom);
        float vx = fmaxf(ax * r + gat_b[2 * l16], 0.f);
        float vy = fmaxf(ay * r + gat_b[2 * l16 + 1], 0.f);
        *(float2*)(out + (size_t)dst * 32 + 2 * l16) = make_float2(vx, vy);
    }
}

// ---------------- launch ----------------
extern "C" void kernel_launch(void* const* d_in, const int* in_sizes, int n_in,
                              void* d_out, int out_size, void* d_ws, size_t ws_size,
                              hipStream_t stream) {
    const int N = NN;

    char* w = (char*)d_ws;
    auto alloc = [&](size_t bytes) {
        void* p = (void*)w;
        w += (bytes + 255) & ~(size_t)255;
        return p;
    };
    int* flags = (int*)alloc(256);
    float* wpool = (float*)alloc((size_t)WTOTAL * 4);
    float* wg = (float*)alloc((size_t)WGTOT * 4);
    float* bg = (float*)alloc(384 * 4);
    float* dis = (float*)alloc((size_t)N * 4);
    int* rptr = (int*)alloc((size_t)(N + 1) * 4);
    int* csr_src = (int*)alloc((size_t)EE * 4);
    unsigned* gh = (unsigned*)alloc((size_t)NBK * 256 * 4);
    unsigned* gh2 = (unsigned*)alloc((size_t)NBK * 256 * 4);
    int* bb = (int*)alloc(1024);
    int2* ebkt = (int2*)alloc((size_t)EE * 8);
    float* asrc = (float*)alloc((size_t)N * 4);
    float* adst = (float*)alloc((size_t)N * 4);
    float* hbuf = (float*)alloc((size_t)N * 32 * 4);       // fp32 N x 32 ping
    unsigned* bufT = (unsigned*)alloc((size_t)N * 64 * 4); // bf16 N x 128
    float* bufH = (float*)alloc((size_t)N * 128 * 4);      // fp32 N x 128

    WSrc ws_srcs;
    for (int i = 0; i < 20; ++i) ws_srcs.p[i] = d_in[2 + i];

    const int AGG = (N + 3) / 4;
    const int TMB = (N + 63) / 64;
    const int WB = (WTOTAL + 255) / 256;

    k_detect<<<1, 256, 0, stream>>>((const unsigned short*)d_in[0],
                                    (const unsigned int*)d_in[1], flags);
    k_cvt_w<<<WB, 256, 0, stream>>>(ws_srcs, wpool, flags, WTOTAL);
    k_prep<<<(WGTOT + 255) / 256, 256, 0, stream>>>(wpool, wg, bg);
    // bucketed CSR build
    k_hist<<<NBK, 256, 0, stream>>>(d_in[1], gh, flags);
    k_bscan<<<1, 256, 0, stream>>>(gh, gh2, bb, rptr);
    k_scatter<<<NBK, 256, 0, stream>>>(d_in[1], gh2, bb, ebkt, flags);
    k_bucket_csr<<<NBK, 256, 0, stream>>>(ebkt, bb, rptr, dis, csr_src);

    // GCN 1 (x -> t1' = (x@W1)*dis, bf16): runtime dtype select inside kernel
    k_tile_mm<128, 128, 2, true, false><<<TMB, 256, 0, stream>>>(
        d_in[0], wpool + OFF_W1, bufT, N, flags, dis, nullptr, nullptr, nullptr);
    k_agg128<true><<<AGG, 256, 0, stream>>>(bufT, rptr, csr_src, dis, wpool + OFF_B1, bufH, N);
    // GCN 2
    k_tile_mm<128, 64, 1, true, false><<<TMB, 256, 0, stream>>>(
        bufH, wpool + OFF_W2, bufT, N, flags, dis, nullptr, nullptr, nullptr);
    k_agg64<true><<<AGG, 256, 0, stream>>>(bufT, rptr, csr_src, dis, wpool + OFF_B2, bufH, N);
    // GCN 3
    k_tile_mm<64, 32, 1, true, false><<<TMB, 256, 0, stream>>>(
        bufH, wpool + OFF_W3, bufT, N, flags, dis, nullptr, nullptr, nullptr);
    k_agg32<false><<<AGG, 256, 0, stream>>>(bufT, rptr, csr_src, dis, wpool + OFF_B3, hbuf, N);
    // GAT matmul (unscaled) + fused attention-vector epilogue
    k_tile_mm<32, 32, 1, false, true><<<TMB, 256, 0, stream>>>(
        hbuf, wpool + OFF_GATW, bufT, N, flags, dis, wpool + OFF_GAS, asrc, adst);
    k_gat_agg<<<AGG, 256, 0, stream>>>(bufT, rptr, csr_src, asrc, adst, wpool + OFF_GAB, hbuf, N);
    // LSTM gates + nonlin + BN + FC (fused, writes d_out)
    k_gates_fc<<<TMB, 256, 0, stream>>>(hbuf, wg, bg, wpool, d_out, flags, N);
}